// Round 8
// baseline (427.619 us; speedup 1.0000x reference)
//
#include <hip/hip_runtime.h>
#include <cstdint>
#include <cstddef>

typedef _Float16 half8 __attribute__((ext_vector_type(8)));
typedef float floatx4 __attribute__((ext_vector_type(4)));

constexpr int N = 16384;
constexpr int H = 4096;
constexpr int E = 64;
constexpr int BM = 32;            // rows per block
constexpr int BK = 256;           // K per stage: 1 KB per row per visit (DRAM page efficiency)
constexpr int NST = H / BK;       // 16 stages
constexpr float XSCALE = 2048.0f;                      // 2^11
constexpr float WSCALE = 4096.0f;                      // 2^12
constexpr float DESCALE = 1.0f / (2048.0f * 4096.0f);  // 2^-23

// LDS: x only, double buffered: 2 x 32 KB (32 rows x 1024 B per buffer).
// 16B-seg swizzle within a row-chunk: phys_seg = log_seg ^ (row&7).
// W is NOT staged: Whi/Wlo fragments load directly from L2 (W is 1 MB,
// fully L2-resident; R5 showed the staged path is not byte-bound).
constexpr int XBUF = 32768;

__device__ __forceinline__ void async16(const void* g, void* l) {
  __builtin_amdgcn_global_load_lds(
      (const __attribute__((address_space(1))) void*)g,
      (__attribute__((address_space(3))) void*)l,
      16, 0, 0);
}

// ---------------- W split prekernel: W (f32) -> Whi + Wlo (f16), scaled by 2^12
__global__ __launch_bounds__(256) void wsplit_kernel(const float* __restrict__ W,
                                                     _Float16* __restrict__ Whi,
                                                     _Float16* __restrict__ Wlo) {
  int i = blockIdx.x * 256 + threadIdx.x;
  if (i >= E * H) return;
  float w = W[i] * WSCALE;
  _Float16 hi = (_Float16)w;
  _Float16 lo = (_Float16)(w - (float)hi);
  Whi[i] = hi;
  Wlo[i] = lo;
}

// split 8 f32 x-values (scaled by 2^11) into f16 hi/lo fragments
__device__ __forceinline__ void cvt_split(const float4& a, const float4& b,
                                          half8& hi, half8& lo) {
  float f[8] = {a.x, a.y, a.z, a.w, b.x, b.y, b.z, b.w};
#pragma unroll
  for (int i = 0; i < 8; ++i) {
    float s = f[i] * XSCALE;
    _Float16 h = (_Float16)s;
    _Float16 l = (_Float16)(s - (float)h);
    hi[i] = h;
    lo[i] = l;
  }
}

// Fused GEMM + softmax + top-2 kernel.
// Grid = N/BM = 512 blocks x 512 threads -> 2 blocks/CU, 16 waves/CU (proven).
// x staged via global_load_lds in 1 KB-per-row chunks (BK=256): 4x the
// per-DRAM-page-visit contiguity of the BK=64 variants (R7 post-mortem:
// 256B-per-16KB-stride visits pay a page activation per chunk -> ~55%
// DRAM efficiency; this was the ~30us kernel-side gap all schedules shared).
// W fragments load per-window directly from L2 to registers.
// Per stage: 4 windows of K=64; wave split kh = wv>>2 (K-subhalf of each
// window), rb = ((wv>>1)&1)*16 (row group), eb = (wv&1)*32 (expert half).
// Summation order per row identical to the BK=64 variants -> same absmax.
__global__ __launch_bounds__(512, 4) void gemm_kernel(
    const float* __restrict__ x,
    const _Float16* __restrict__ Whi,
    const _Float16* __restrict__ Wlo,
    float* __restrict__ out_scores,
    float* __restrict__ out_w,
    float* __restrict__ out_i) {
  __shared__ __align__(16) char smem[2 * XBUF];

  const int tid = threadIdx.x;
  const int wv = tid >> 6;
  const int lane = tid & 63;
  const int c = lane & 15;
  const int q = lane >> 4;
  const int r0 = blockIdx.x * BM;

  // ---- x staging: 4 async16 per thread per stage (32 KB / (512 thr x 16 B)) ----
  // issue j covers rows j*8 .. j*8+7: thread t -> row j*8 + (t>>6),
  // phys seg t&63, log seg = phys ^ (row&7) = (t&63) ^ ((t>>6)&7)  (j*8 = 0 mod 8)
  const int trow = tid >> 6;
  const int lseg = (tid & 63) ^ (trow & 7);
  const float* gx = x + (size_t)r0 * H + lseg * 4;
  auto stage = [&](int s, int b) {
    const float* gs = gx + s * BK;
    char* base = smem + b * XBUF;
#pragma unroll
    for (int j = 0; j < 4; ++j)
      async16(gs + (size_t)(j * 8 + trow) * H, base + j * 8192 + tid * 16);
  };

  // ---- fragment addressing ----
  const int kh = wv >> 2;
  const int rb = ((wv >> 1) & 1) << 4;
  const int eb = (wv & 1) << 5;
  const int row = rb + c;
  const int rx = row & 7;
  // W direct-from-L2 pointers (per lane): expert rows eb+c and eb+16+c,
  // K base = kh*32 + q*8 within each 64-wide window
  const _Float16* wh0 = Whi + (size_t)(eb + c) * H + kh * 32 + q * 8;
  const _Float16* wh1 = wh0 + (size_t)16 * H;
  const _Float16* wl0 = Wlo + (size_t)(eb + c) * H + kh * 32 + q * 8;
  const _Float16* wl1 = wl0 + (size_t)16 * H;

  floatx4 acc0 = {0.f, 0.f, 0.f, 0.f};
  floatx4 acc1 = acc0;

  auto compute = [&](int s, int b) {
    const char* xb = smem + b * XBUF + row * 1024;
#pragma unroll
    for (int w = 0; w < 4; ++w) {
      const int ko = s * BK + w * 64;  // f16/f32 element offset along K
      half8 h0 = *(const half8*)(wh0 + ko);
      half8 h1 = *(const half8*)(wh1 + ko);
      half8 l0 = *(const half8*)(wl0 + ko);
      half8 l1 = *(const half8*)(wl1 + ko);
      const int sg = w * 16 + kh * 8 + q * 2;
      float4 xa = *(const float4*)(xb + ((sg ^ rx) * 16));
      float4 xb4 = *(const float4*)(xb + (((sg + 1) ^ rx) * 16));

      half8 ahi, alo;
      cvt_split(xa, xb4, ahi, alo);

      acc0 = __builtin_amdgcn_mfma_f32_16x16x32_f16(alo, h0, acc0, 0, 0, 0);
      acc1 = __builtin_amdgcn_mfma_f32_16x16x32_f16(alo, h1, acc1, 0, 0, 0);
      acc0 = __builtin_amdgcn_mfma_f32_16x16x32_f16(ahi, l0, acc0, 0, 0, 0);
      acc1 = __builtin_amdgcn_mfma_f32_16x16x32_f16(ahi, l1, acc1, 0, 0, 0);
      acc0 = __builtin_amdgcn_mfma_f32_16x16x32_f16(ahi, h0, acc0, 0, 0, 0);
      acc1 = __builtin_amdgcn_mfma_f32_16x16x32_f16(ahi, h1, acc1, 0, 0, 0);
    }
  };

  stage(0, 0);
  for (int s = 0; s < NST; ++s) {
    const int b = s & 1;
    __syncthreads();                       // drains stage s's DMA (m97 pattern)
    if (s + 1 < NST) stage(s + 1, b ^ 1);  // next stage in flight during compute
    compute(s, b);
  }

  // ---- reduce the 2 K-subhalves in LDS ----
  __syncthreads();            // everyone done reading buffers (red aliases them)
  float* red = (float*)smem;  // [2][32][64] = 16 KB
#pragma unroll
  for (int r = 0; r < 4; ++r) {
    const int rrow = rb + q * 4 + r;
    float* rp = red + (kh * 32 + rrow) * 64 + eb;
    rp[0 * 16 + c] = acc0[r];
    rp[1 * 16 + c] = acc1[r];
  }
  __syncthreads();

  // ---- fused finalize: 8 waves x 4 rows; lane = expert ----
  const int rbase = wv * 4;
  for (int rr = rbase; rr < rbase + 4; ++rr) {
    float v = (red[rr * 64 + lane] + red[(32 + rr) * 64 + lane]) * DESCALE;
    // softmax
    float m = v;
#pragma unroll
    for (int o = 32; o > 0; o >>= 1) m = fmaxf(m, __shfl_xor(m, o));
    float ev = __expf(v - m);
    float ssum = ev;
#pragma unroll
    for (int o = 32; o > 0; o >>= 1) ssum += __shfl_xor(ssum, o);
    out_scores[(size_t)(r0 + rr) * E + lane] = ev / ssum;
    // top-2 butterfly with (value desc, index asc) order — matches lax.top_k
    float v1 = v;
    int i1 = lane;
    float v2 = -3.4e38f;
    int i2 = E;
#pragma unroll
    for (int o = 32; o > 0; o >>= 1) {
      float w1 = __shfl_xor(v1, o);
      int j1 = __shfl_xor(i1, o);
      float w2 = __shfl_xor(v2, o);
      int j2 = __shfl_xor(i2, o);
      bool firstBetter = (v1 > w1) || (v1 == w1 && i1 < j1);
      float t1, t2;
      int ti1, ti2;
      if (firstBetter) {
        t1 = v1; ti1 = i1;
        bool sec = (v2 > w1) || (v2 == w1 && i2 < j1);
        t2 = sec ? v2 : w1;
        ti2 = sec ? i2 : j1;
      } else {
        t1 = w1; ti1 = j1;
        bool sec = (w2 > v1) || (w2 == v1 && j2 < i1);
        t2 = sec ? w2 : v1;
        ti2 = sec ? j2 : i1;
      }
      v1 = t1; i1 = ti1; v2 = t2; i2 = ti2;
    }
    if (lane == 0) {
      float e1 = __expf(v1 - m);
      float e2 = __expf(v2 - m);
      float inv = 1.0f / (e1 + e2);
      size_t o2 = (size_t)(r0 + rr) * 2;
      out_w[o2] = e1 * inv;
      out_w[o2 + 1] = e2 * inv;
      out_i[o2] = (float)i1;
      out_i[o2 + 1] = (float)i2;
    }
  }
}

extern "C" void kernel_launch(void* const* d_in, const int* in_sizes, int n_in,
                              void* d_out, int out_size, void* d_ws, size_t ws_size,
                              hipStream_t stream) {
  const float* x = (const float*)d_in[0];
  const float* W = (const float*)d_in[1];
  float* out = (float*)d_out;
  float* out_scores = out;                  // [N, 64]
  float* out_w = out + (size_t)N * E;       // [N, 2]
  float* out_i = out_w + (size_t)N * 2;     // [N, 2] (indices as floats)
  _Float16* Whi = (_Float16*)d_ws;          // 512 KB
  _Float16* Wlo = Whi + (size_t)E * H;      // 512 KB

  wsplit_kernel<<<(E * H + 255) / 256, 256, 0, stream>>>(W, Whi, Wlo);
  gemm_kernel<<<N / BM, 512, 0, stream>>>(x, Whi, Wlo, out_scores, out_w, out_i);
}

// Round 9
// 387.730 us; speedup vs baseline: 1.1029x; 1.1029x over previous
//
#include <hip/hip_runtime.h>
#include <cstdint>
#include <cstddef>

typedef _Float16 half8 __attribute__((ext_vector_type(8)));
typedef float floatx4 __attribute__((ext_vector_type(4)));

constexpr int N = 16384;
constexpr int H = 4096;
constexpr int E = 64;
constexpr int BM = 32;            // rows per block
constexpr int KS = 2;             // split-K factor
constexpr int KPB = H / KS;       // 2048 K per block
constexpr int BK = 64;            // K per stage
constexpr int NST = KPB / BK;     // 32 stages
constexpr float XSCALE = 2048.0f;                      // 2^11
constexpr float WSCALE = 4096.0f;                      // 2^12
constexpr float DESCALE = 1.0f / (2048.0f * 4096.0f);  // 2^-23

// LDS per block = 32 KB -> 4 blocks/CU (128 KB), 32 waves/CU = MAX occupancy.
//   x   : 2 x 8 KB [0, 16384)      buf s&1; 32 rows x 256 B; seg swz ^(row&7)
//   Whi : 8 KB     [16384, 24576)  SINGLE-buffered (L2-resident source)
//   Wlo : 8 KB     [24576, 32768)
constexpr int XB = 8192;
constexpr int WHIO = 16384;
constexpr int WLOO = 24576;

__device__ __forceinline__ void async16(const void* g, void* l) {
  __builtin_amdgcn_global_load_lds(
      (const __attribute__((address_space(1))) void*)g,
      (__attribute__((address_space(3))) void*)l,
      16, 0, 0);
}

// ---------------- W split prekernel: W (f32) -> Whi + Wlo (f16), scaled by 2^12
__global__ __launch_bounds__(256) void wsplit_kernel(const float* __restrict__ W,
                                                     _Float16* __restrict__ Whi,
                                                     _Float16* __restrict__ Wlo) {
  int i = blockIdx.x * 256 + threadIdx.x;
  if (i >= E * H) return;
  float w = W[i] * WSCALE;
  _Float16 hi = (_Float16)w;
  _Float16 lo = (_Float16)(w - (float)hi);
  Whi[i] = hi;
  Wlo[i] = lo;
}

// split 8 f32 x-values (scaled by 2^11) into f16 hi/lo fragments
__device__ __forceinline__ void cvt_split(const float4& a, const float4& b,
                                          half8& hi, half8& lo) {
  float f[8] = {a.x, a.y, a.z, a.w, b.x, b.y, b.z, b.w};
#pragma unroll
  for (int i = 0; i < 8; ++i) {
    float s = f[i] * XSCALE;
    _Float16 h = (_Float16)s;
    _Float16 l = (_Float16)(s - (float)h);
    hi[i] = h;
    lo[i] = l;
  }
}

// Split-K GEMM. Grid = (N/BM)*KS = 1024 blocks x 512 threads -> 4 blocks/CU,
// 32 waves/CU (R8 counters: Occupancy 39%, all pipes <15% busy at 16 waves ->
// latency-bound; occupancy is the one lever that ever moved the needle).
// Per stage s:
//   [vmcnt(1); s_barrier]   queue = [x(s), W(s), x(s+1)] -> retires x(s), W(s)
//   ds_reads of x(s), W
//   [lgkmcnt(0); s_barrier] all waves' reads retired -> W buf free to overwrite
//   issue W(s+1) -> fixed W buf; SB(0); issue x(s+2) -> x buf s&1 (just read)
//   cvt + 6 MFMA             (covers W's L2 latency; x has ~1.5 stages flight)
// vmcnt never drains to 0 mid-loop (T4); issue order pinned (in-order vmcnt).
// Wave split: kh = wv>>2 (K-subhalf), rb = ((wv>>1)&1)*16, eb = (wv&1)*32.
__global__ __launch_bounds__(512, 8) void gemm_kernel(
    const float* __restrict__ x,
    const _Float16* __restrict__ Whi,
    const _Float16* __restrict__ Wlo,
    float* __restrict__ part) {
  __shared__ __align__(16) char smem[32768];

  const int tid = threadIdx.x;
  const int wv = tid >> 6;
  const int lane = tid & 63;
  const int c = lane & 15;
  const int q = lane >> 4;
  const int rowtile = blockIdx.x >> 1;
  const int ks = blockIdx.x & 1;
  const int r0 = rowtile * BM;
  const int k0 = ks * KPB;

  // ---- staging addresses: 3 async16 per thread per stage ----
  // x (8 KB = 1 load): t -> row t>>4 (0..31), phys seg t&15, log = phys^(row&7)
  const int xr = tid >> 4;
  const float* gx = x + (size_t)(r0 + xr) * H + k0 + (((tid & 15) ^ (xr & 7)) * 4);
  // Whi/Wlo (8 KB each = 1 load): t -> expert t>>3, phys seg t&7, log = phys^(e&7)
  const int we = tid >> 3;
  const int wlog = (tid & 7) ^ (we & 7);
  const _Float16* gwh = Whi + (size_t)we * H + k0 + wlog * 8;
  const _Float16* gwl = Wlo + (size_t)we * H + k0 + wlog * 8;
  const int xd = tid * 16;
  const int wd = tid * 16;

  // ---- fragment LDS byte offsets ----
  const int kh = wv >> 2;
  const int rb = ((wv >> 1) & 1) << 4;
  const int eb = (wv & 1) << 5;
  const int fr = rb + c;
  const int sA = 8 * kh + 2 * q;
  const int xo0 = fr * 256 + ((sA ^ (fr & 7)) * 16);
  const int xo1 = fr * 256 + (((sA + 1) ^ (fr & 7)) * 16);
  const int wph = ((4 * kh + q) ^ (c & 7)) * 16;
  const int wo0 = (eb + 0 * 16 + c) * 128 + wph;
  const int wo1 = (eb + 1 * 16 + c) * 128 + wph;

  auto stageX = [&](int s) {
    async16(gx + s * BK, smem + (s & 1) * XB + xd);
  };
  auto stageW = [&](int s) {
    const int kc = s * BK;
    async16(gwh + kc, smem + WHIO + wd);
    async16(gwl + kc, smem + WLOO + wd);
  };

  floatx4 acc0 = {0.f, 0.f, 0.f, 0.f};
  floatx4 acc1 = acc0;

  auto step = [&](int s, bool last) {
    if (!last)
      asm volatile("s_waitcnt vmcnt(1)\n\ts_barrier" ::: "memory");
    else
      asm volatile("s_waitcnt vmcnt(0)\n\ts_barrier" ::: "memory");
    const char* xb = smem + (s & 1) * XB;
    float4 xa = *(const float4*)(xb + xo0);
    float4 xv = *(const float4*)(xb + xo1);
    half8 h0 = *(const half8*)(smem + WHIO + wo0);
    half8 h1 = *(const half8*)(smem + WHIO + wo1);
    half8 l0 = *(const half8*)(smem + WLOO + wo0);
    half8 l1 = *(const half8*)(smem + WLOO + wo1);
    asm volatile("s_waitcnt lgkmcnt(0)\n\ts_barrier" ::: "memory");
    if (s + 1 < NST) stageW(s + 1);     // W queue-slot BEFORE x (in-order vmcnt)
    __builtin_amdgcn_sched_barrier(0);
    if (s + 2 < NST) stageX(s + 2);

    half8 ahi, alo;
    cvt_split(xa, xv, ahi, alo);
    acc0 = __builtin_amdgcn_mfma_f32_16x16x32_f16(alo, h0, acc0, 0, 0, 0);
    acc1 = __builtin_amdgcn_mfma_f32_16x16x32_f16(alo, h1, acc1, 0, 0, 0);
    acc0 = __builtin_amdgcn_mfma_f32_16x16x32_f16(ahi, l0, acc0, 0, 0, 0);
    acc1 = __builtin_amdgcn_mfma_f32_16x16x32_f16(ahi, l1, acc1, 0, 0, 0);
    acc0 = __builtin_amdgcn_mfma_f32_16x16x32_f16(ahi, h0, acc0, 0, 0, 0);
    acc1 = __builtin_amdgcn_mfma_f32_16x16x32_f16(ahi, h1, acc1, 0, 0, 0);
  };

  // ---- prologue: queue = [W(0)hi, W(0)lo ... counts as stage-W slot, x(0), x(1)]
  // NB: vmcnt counts instructions; W = 2 loads. At top of stage s the queue is
  // [Wh(s), Wl(s), x(s)... ] -- order W-first at prologue, then x(0), x(1):
  // stage 0 wait must retire Wh0, Wl0, x0 and keep x1 -> vmcnt(1). In steady
  // state queue at top of s: [x(s), Wh(s), Wl(s), x(s+1)] -> vmcnt(1). Same N.
  stageW(0);
  __builtin_amdgcn_sched_barrier(0);
  stageX(0);
  __builtin_amdgcn_sched_barrier(0);
  stageX(1);

  for (int s = 0; s < NST - 1; ++s) step(s, false);
  step(NST - 1, true);

  // ---- reduce the 2 K-subhalves in LDS, write block partial ----
  // red (16 KB) aliases the two x buffers; all x ds_reads retired before the
  // final lgkmcnt(0)+barrier, and no DMA is outstanding after the last step.
  float* red = (float*)smem;  // [2][32][64]
#pragma unroll
  for (int r = 0; r < 4; ++r) {
    const int row = rb + q * 4 + r;
    float* rp = red + (kh * 32 + row) * 64 + eb;
    rp[0 * 16 + c] = acc0[r];
    rp[1 * 16 + c] = acc1[r];
  }
  __syncthreads();

  // 8 waves x 4 rows; lane = expert
  const int rbase = wv * 4;
#pragma unroll
  for (int rr = rbase; rr < rbase + 4; ++rr) {
    float v = red[rr * 64 + lane] + red[(32 + rr) * 64 + lane];
    part[((size_t)ks * N + r0 + rr) * 64 + lane] = v;
  }
}

// Finalize: reduce split-K partials, softmax, top-2. Grid 4096 x 256 (wave/row).
// Verbatim R0-proven kernel.
__global__ __launch_bounds__(256) void finalize_kernel(
    const float* __restrict__ part,
    float* __restrict__ out_scores,
    float* __restrict__ out_w,
    float* __restrict__ out_i) {
  const int wv = threadIdx.x >> 6;
  const int lane = threadIdx.x & 63;
  const int row = blockIdx.x * 4 + wv;

  float v = part[(size_t)row * 64 + lane] +
            part[((size_t)N + row) * 64 + lane];
  v *= DESCALE;
  // softmax
  float m = v;
#pragma unroll
  for (int o = 32; o > 0; o >>= 1) m = fmaxf(m, __shfl_xor(m, o));
  float ev = __expf(v - m);
  float ssum = ev;
#pragma unroll
  for (int o = 32; o > 0; o >>= 1) ssum += __shfl_xor(ssum, o);
  out_scores[(size_t)row * E + lane] = ev / ssum;
  // top-2 butterfly with (value desc, index asc) order — matches lax.top_k
  float v1 = v;
  int i1 = lane;
  float v2 = -3.4e38f;
  int i2 = E;
#pragma unroll
  for (int o = 32; o > 0; o >>= 1) {
    float w1 = __shfl_xor(v1, o);
    int j1 = __shfl_xor(i1, o);
    float w2 = __shfl_xor(v2, o);
    int j2 = __shfl_xor(i2, o);
    bool firstBetter = (v1 > w1) || (v1 == w1 && i1 < j1);
    float t1, t2;
    int ti1, ti2;
    if (firstBetter) {
      t1 = v1; ti1 = i1;
      bool sec = (v2 > w1) || (v2 == w1 && i2 < j1);
      t2 = sec ? v2 : w1;
      ti2 = sec ? i2 : j1;
    } else {
      t1 = w1; ti1 = j1;
      bool sec = (w2 > v1) || (w2 == v1 && j2 < i1);
      t2 = sec ? w2 : v1;
      ti2 = sec ? j2 : i1;
    }
    v1 = t1; i1 = ti1; v2 = t2; i2 = ti2;
  }
  if (lane == 0) {
    float e1 = __expf(v1 - m);
    float e2 = __expf(v2 - m);
    float inv = 1.0f / (e1 + e2);
    size_t o2 = (size_t)row * 2;
    out_w[o2] = e1 * inv;
    out_w[o2 + 1] = e2 * inv;
    out_i[o2] = (float)i1;
    out_i[o2 + 1] = (float)i2;
  }
}

extern "C" void kernel_launch(void* const* d_in, const int* in_sizes, int n_in,
                              void* d_out, int out_size, void* d_ws, size_t ws_size,
                              hipStream_t stream) {
  const float* x = (const float*)d_in[0];
  const float* W = (const float*)d_in[1];
  float* out = (float*)d_out;
  float* out_scores = out;                  // [N, 64]
  float* out_w = out + (size_t)N * E;       // [N, 2]
  float* out_i = out_w + (size_t)N * 2;     // [N, 2] (indices as floats)
  _Float16* Whi = (_Float16*)d_ws;          // 512 KB
  _Float16* Wlo = Whi + (size_t)E * H;      // 512 KB
  float* part = (float*)((char*)d_ws + 2 * 1024 * 1024);  // [KS][N][E] = 8 MB

  wsplit_kernel<<<(E * H + 255) / 256, 256, 0, stream>>>(W, Whi, Wlo);
  gemm_kernel<<<(N / BM) * KS, 512, 0, stream>>>(x, Whi, Wlo, part);
  finalize_kernel<<<N / 4, 256, 0, stream>>>(part, out_scores, out_w, out_i);
}